// Round 1
// baseline (1764.542 us; speedup 1.0000x reference)
//
#include <hip/hip_runtime.h>
#include <hip/hip_bf16.h>

// SAGEMean3: h = [x | mean_in | mean_out] (50000 x 384), out = relu(h @ W + b)
// Baseline structure:
//   1. memset sums/counts in ws
//   2. scatter: wave per edge, fp32 atomics into sum_in/sum_out + counts
//   3. build_h: bf16 h rows (x | sum_in/cnt | sum_out/cnt), stride 384
//   4. wt: W [384x1024] fp32 -> Wt [1024x384] bf16 (so B-frag loads are contiguous)
//   5. gemm: wave per 16x16 output tile, mfma_f32_16x16x32_bf16, K=384 (12 steps),
//      fused bias + relu, fp32 out.

typedef __attribute__((ext_vector_type(8))) short bf16x8;   // 8 bf16 in 4 VGPRs
typedef __attribute__((ext_vector_type(4))) float f32x4;

#define IN_DIM 128
#define K3 384
#define ODIM 1024

__global__ __launch_bounds__(256) void sage_scatter(
    const float* __restrict__ x, const int* __restrict__ src, const int* __restrict__ dst,
    float* __restrict__ sum_in, float* __restrict__ sum_out,
    float* __restrict__ cnt_in, float* __restrict__ cnt_out, int n_edges)
{
    int wid  = (int)((blockIdx.x * 256 + threadIdx.x) >> 6);
    int lane = threadIdx.x & 63;
    if (wid >= n_edges) return;
    int s = src[wid];
    int d = dst[wid];
    const float2 vs = ((const float2*)(x + (size_t)s * IN_DIM))[lane];
    const float2 vd = ((const float2*)(x + (size_t)d * IN_DIM))[lane];
    float* pi = sum_in  + (size_t)d * IN_DIM + lane * 2;
    float* po = sum_out + (size_t)s * IN_DIM + lane * 2;
    atomicAdd(pi,     vs.x);
    atomicAdd(pi + 1, vs.y);
    atomicAdd(po,     vd.x);
    atomicAdd(po + 1, vd.y);
    if (lane == 0) {
        atomicAdd(cnt_in + d, 1.0f);
        atomicAdd(cnt_out + s, 1.0f);
    }
}

__global__ __launch_bounds__(256) void sage_build_h(
    const float* __restrict__ x, const float* __restrict__ sum_in,
    const float* __restrict__ sum_out, const float* __restrict__ cnt_in,
    const float* __restrict__ cnt_out, __hip_bfloat16* __restrict__ h, int n_nodes)
{
    int tid = blockIdx.x * 256 + threadIdx.x;
    if (tid >= n_nodes * IN_DIM) return;
    int i   = tid >> 7;      // node
    int dch = tid & 127;     // feature dim
    float ci = fmaxf(cnt_in[i],  1.0f);
    float co = fmaxf(cnt_out[i], 1.0f);
    size_t r = (size_t)i * K3;
    h[r + dch]              = __float2bfloat16(x[tid]);
    h[r + IN_DIM + dch]     = __float2bfloat16(sum_in[tid] / ci);
    h[r + 2 * IN_DIM + dch] = __float2bfloat16(sum_out[tid] / co);
}

__global__ __launch_bounds__(256) void sage_wt(
    const float* __restrict__ W, __hip_bfloat16* __restrict__ Wt)
{
    int tid = blockIdx.x * 256 + threadIdx.x;   // over K3*ODIM
    int k  = tid / ODIM;
    int nn = tid % ODIM;
    Wt[(size_t)nn * K3 + k] = __float2bfloat16(W[tid]);
}

// Wave computes one 16x16 output tile. A-frag: A[m=lane&15][k=quad*8+j];
// B-frag: B[k=quad*8+j][n=lane&15] == contiguous row read of Wt[n][k].
// C/D: col=lane&15, row=quad*4+reg.
__global__ __launch_bounds__(256) void sage_gemm(
    const __hip_bfloat16* __restrict__ h, const __hip_bfloat16* __restrict__ Wt,
    const float* __restrict__ bias, float* __restrict__ out, int tiles_m)
{
    int wid  = (int)((blockIdx.x * 256 + threadIdx.x) >> 6);
    int lane = threadIdx.x & 63;
    int tn = wid & 63;           // 64 n-tiles (ODIM/16)
    int tm = wid >> 6;
    if (tm >= tiles_m) return;
    int m    = lane & 15;        // doubles as n_local for the B fragment
    int quad = lane >> 4;

    const bf16x8* ha = (const bf16x8*)(h  + (size_t)(tm * 16 + m) * K3 + quad * 8);
    const bf16x8* wb = (const bf16x8*)(Wt + (size_t)(tn * 16 + m) * K3 + quad * 8);

    f32x4 acc = {0.f, 0.f, 0.f, 0.f};
#pragma unroll
    for (int kk = 0; kk < K3 / 32; ++kk) {
        bf16x8 a = ha[kk * 4];   // advance 32 bf16 per step
        bf16x8 b = wb[kk * 4];
        acc = __builtin_amdgcn_mfma_f32_16x16x32_bf16(a, b, acc, 0, 0, 0);
    }

    int col  = tn * 16 + m;
    float bv = bias[col];
    int row0 = tm * 16 + quad * 4;
#pragma unroll
    for (int r = 0; r < 4; ++r) {
        float v = acc[r] + bv;
        out[(size_t)(row0 + r) * ODIM + col] = fmaxf(v, 0.f);
    }
}

extern "C" void kernel_launch(void* const* d_in, const int* in_sizes, int n_in,
                              void* d_out, int out_size, void* d_ws, size_t ws_size,
                              hipStream_t stream)
{
    const float* x    = (const float*)d_in[0];
    const int*   ei   = (const int*)d_in[1];
    const float* W    = (const float*)d_in[2];
    const float* bias = (const float*)d_in[3];

    int n_nodes = in_sizes[0] / IN_DIM;
    int n_edges = in_sizes[1] / 2;
    const int* src = ei;
    const int* dst = ei + n_edges;

    // Workspace layout (bytes):
    //   sum_in  : n*128*4          = 25.6 MB
    //   sum_out : n*128*4          = 25.6 MB
    //   cnt_in  : n*4
    //   cnt_out : n*4
    //   h(bf16) : n*384*2          = 38.4 MB
    //   Wt(bf16): 384*1024*2       = 0.77 MB     total ~90.8 MB
    size_t NS = (size_t)n_nodes * IN_DIM * sizeof(float);
    char* ws = (char*)d_ws;
    float* sum_in  = (float*)ws;
    float* sum_out = (float*)(ws + NS);
    float* cnt_in  = (float*)(ws + 2 * NS);
    float* cnt_out = (float*)(ws + 2 * NS + (size_t)n_nodes * sizeof(float));
    __hip_bfloat16* h  = (__hip_bfloat16*)(ws + 2 * NS + 2 * (size_t)n_nodes * sizeof(float));
    __hip_bfloat16* Wt = (__hip_bfloat16*)((char*)h + (size_t)n_nodes * K3 * sizeof(__hip_bfloat16));

    hipMemsetAsync(d_ws, 0, 2 * NS + 2 * (size_t)n_nodes * sizeof(float), stream);

    // one wave per edge
    sage_scatter<<<(n_edges + 3) / 4, 256, 0, stream>>>(
        x, src, dst, sum_in, sum_out, cnt_in, cnt_out, n_edges);

    sage_build_h<<<(n_nodes * IN_DIM + 255) / 256, 256, 0, stream>>>(
        x, sum_in, sum_out, cnt_in, cnt_out, h, n_nodes);

    sage_wt<<<(K3 * ODIM) / 256, 256, 0, stream>>>(W, Wt);

    int tiles_m = n_nodes / 16;          // 50000/16 = 3125 exact
    int waves   = tiles_m * (ODIM / 16); // * 64 n-tiles
    sage_gemm<<<(waves + 3) / 4, 256, 0, stream>>>(h, Wt, bias, (float*)d_out, tiles_m);
}

// Round 2
// 598.484 us; speedup vs baseline: 2.9484x; 2.9484x over previous
//
#include <hip/hip_runtime.h>
#include <hip/hip_bf16.h>

// SAGEMean3: h = [x | mean_in | mean_out] (50000 x 384), out = relu(h @ W + b)
// R1 structure:
//   1. memset deg/cursor (1.6 MB)
//   2. degree histogram (int atomics)
//   3. 3-kernel exclusive scan over concatenated deg[2N] -> off[2N]
//   4. CSR fill (cursor atomics); in-lists at [off[i]..), out-lists at [off[N+i]..)
//   5. aggregate: one wave per node, gather x[nbr] rows, mean, write bf16 h directly
//   6. W -> Wt bf16 transpose
//   7. GEMM: one wave per 64x64 output tile = 4x4 grid of 16x16x32 bf16 MFMA,
//      fused bias + relu. A-frag A[m=lane&15][k=quad*8+j]; B-frag = contiguous
//      Wt row read; C/D col=lane&15, row=quad*4+reg (verified in R0).

typedef __attribute__((ext_vector_type(8))) short bf16x8;
typedef __attribute__((ext_vector_type(4))) float f32x4;

#define IN_DIM 128
#define K3 384
#define ODIM 1024

__global__ __launch_bounds__(256) void sage_degree(
    const int* __restrict__ src, const int* __restrict__ dst,
    int* __restrict__ deg, int n_nodes, int n_edges)
{
    int t = blockIdx.x * 256 + threadIdx.x;
    if (t >= n_edges) return;
    atomicAdd(deg + dst[t], 1);            // in-degree of dst
    atomicAdd(deg + n_nodes + src[t], 1);  // out-degree of src
}

// block-level exclusive scan: 1024 elements per 256-thread block
__global__ __launch_bounds__(256) void scan_partial(
    const int* __restrict__ deg, int* __restrict__ off, int* __restrict__ bsum, int n)
{
    __shared__ int s[256];
    int t = threadIdx.x;
    int base = blockIdx.x * 1024 + t * 4;
    int4 v = {0, 0, 0, 0};
    if (base + 3 < n) v = *(const int4*)(deg + base);
    else {
        if (base     < n) v.x = deg[base];
        if (base + 1 < n) v.y = deg[base + 1];
        if (base + 2 < n) v.z = deg[base + 2];
        if (base + 3 < n) v.w = deg[base + 3];
    }
    int tsum = v.x + v.y + v.z + v.w;
    s[t] = tsum;
    __syncthreads();
#pragma unroll
    for (int d = 1; d < 256; d <<= 1) {
        int add = (t >= d) ? s[t - d] : 0;
        __syncthreads();
        s[t] += add;
        __syncthreads();
    }
    int excl = s[t] - tsum;
    if (t == 255) bsum[blockIdx.x] = s[255];
    int e0 = excl, e1 = e0 + v.x, e2 = e1 + v.y, e3 = e2 + v.z;
    if (base     < n) off[base]     = e0;
    if (base + 1 < n) off[base + 1] = e1;
    if (base + 2 < n) off[base + 2] = e2;
    if (base + 3 < n) off[base + 3] = e3;
}

__global__ __launch_bounds__(256) void scan_bsum(int* __restrict__ bsum, int nblk)
{
    __shared__ int s[256];
    int t = threadIdx.x;
    int v = (t < nblk) ? bsum[t] : 0;
    s[t] = v;
    __syncthreads();
#pragma unroll
    for (int d = 1; d < 256; d <<= 1) {
        int add = (t >= d) ? s[t - d] : 0;
        __syncthreads();
        s[t] += add;
        __syncthreads();
    }
    if (t < nblk) bsum[t] = s[t] - v;   // exclusive
}

__global__ __launch_bounds__(256) void scan_add(
    int* __restrict__ off, const int* __restrict__ bsum, int n)
{
    int base = blockIdx.x * 1024 + threadIdx.x * 4;
    int b = bsum[blockIdx.x];
#pragma unroll
    for (int j = 0; j < 4; ++j)
        if (base + j < n) off[base + j] += b;
}

__global__ __launch_bounds__(256) void sage_fill(
    const int* __restrict__ src, const int* __restrict__ dst,
    const int* __restrict__ off, int* __restrict__ cursor,
    int* __restrict__ csr, int n_nodes, int n_edges)
{
    int t = blockIdx.x * 256 + threadIdx.x;
    if (t >= n_edges) return;
    int s = src[t];
    int d = dst[t];
    int p0 = atomicAdd(cursor + d, 1);
    csr[off[d] + p0] = s;                        // in-neighbor of d
    int p1 = atomicAdd(cursor + n_nodes + s, 1);
    csr[off[n_nodes + s] + p1] = d;              // out-neighbor of s
}

// one wave per node: gather + mean both directions, write bf16 h row
__global__ __launch_bounds__(256) void sage_aggregate(
    const float* __restrict__ x, const int* __restrict__ csr,
    const int* __restrict__ off, const int* __restrict__ deg,
    __hip_bfloat16* __restrict__ h, int n_nodes)
{
    int wid  = (int)((blockIdx.x * 256 + threadIdx.x) >> 6);
    int lane = threadIdx.x & 63;
    if (wid >= n_nodes) return;
    int i = wid;

    float2 ai = {0.f, 0.f}, ao = {0.f, 0.f};
    int b0 = off[i],           d0 = deg[i];
    int b1 = off[n_nodes + i], d1 = deg[n_nodes + i];

    int e = 0;
    for (; e + 1 < d0; e += 2) {
        int nb0 = csr[b0 + e], nb1 = csr[b0 + e + 1];
        float2 v0 = *(const float2*)(x + (size_t)nb0 * IN_DIM + lane * 2);
        float2 v1 = *(const float2*)(x + (size_t)nb1 * IN_DIM + lane * 2);
        ai.x += v0.x + v1.x; ai.y += v0.y + v1.y;
    }
    if (e < d0) {
        int nb = csr[b0 + e];
        float2 v = *(const float2*)(x + (size_t)nb * IN_DIM + lane * 2);
        ai.x += v.x; ai.y += v.y;
    }
    e = 0;
    for (; e + 1 < d1; e += 2) {
        int nb0 = csr[b1 + e], nb1 = csr[b1 + e + 1];
        float2 v0 = *(const float2*)(x + (size_t)nb0 * IN_DIM + lane * 2);
        float2 v1 = *(const float2*)(x + (size_t)nb1 * IN_DIM + lane * 2);
        ao.x += v0.x + v1.x; ao.y += v0.y + v1.y;
    }
    if (e < d1) {
        int nb = csr[b1 + e];
        float2 v = *(const float2*)(x + (size_t)nb * IN_DIM + lane * 2);
        ao.x += v.x; ao.y += v.y;
    }

    float inv0 = 1.0f / (float)max(d0, 1);
    float inv1 = 1.0f / (float)max(d1, 1);
    float2 xv = *(const float2*)(x + (size_t)i * IN_DIM + lane * 2);

    __hip_bfloat162* hp = (__hip_bfloat162*)(h + (size_t)i * K3);
    __hip_bfloat162 p;
    p.x = __float2bfloat16(xv.x);        p.y = __float2bfloat16(xv.y);
    hp[lane] = p;
    p.x = __float2bfloat16(ai.x * inv0); p.y = __float2bfloat16(ai.y * inv0);
    hp[64 + lane] = p;
    p.x = __float2bfloat16(ao.x * inv1); p.y = __float2bfloat16(ao.y * inv1);
    hp[128 + lane] = p;
}

__global__ __launch_bounds__(256) void sage_wt(
    const float* __restrict__ W, __hip_bfloat16* __restrict__ Wt)
{
    int tid = blockIdx.x * 256 + threadIdx.x;   // over K3*ODIM
    int k  = tid / ODIM;
    int nn = tid % ODIM;
    Wt[(size_t)nn * K3 + k] = __float2bfloat16(W[tid]);
}

// wave computes 64x64 outputs: 4x4 subtiles of 16x16, 16 accumulators
__global__ __launch_bounds__(256) void sage_gemm(
    const __hip_bfloat16* __restrict__ h, const __hip_bfloat16* __restrict__ Wt,
    const float* __restrict__ bias, float* __restrict__ out, int n_nodes, int tiles_m)
{
    int wid  = (int)((blockIdx.x * 256 + threadIdx.x) >> 6);
    int lane = threadIdx.x & 63;
    const int tiles_n = ODIM / 64;    // 16
    int tn = wid % tiles_n;
    int tm = wid / tiles_n;
    if (tm >= tiles_m) return;
    int m    = lane & 15;
    int quad = lane >> 4;

    const __hip_bfloat16* pa[4];
    const __hip_bfloat16* pb[4];
#pragma unroll
    for (int s = 0; s < 4; ++s) {
        int r = tm * 64 + s * 16 + m;
        if (r >= n_nodes) r = n_nodes - 1;                 // clamp; stores guarded
        pa[s] = h  + (size_t)r * K3 + quad * 8;
        pb[s] = Wt + (size_t)(tn * 64 + s * 16 + m) * K3 + quad * 8;
    }

    f32x4 acc[4][4];
#pragma unroll
    for (int s = 0; s < 4; ++s)
#pragma unroll
        for (int t = 0; t < 4; ++t) acc[s][t] = (f32x4){0.f, 0.f, 0.f, 0.f};

#pragma unroll
    for (int kk = 0; kk < K3 / 32; ++kk) {
        bf16x8 a[4], b[4];
#pragma unroll
        for (int s = 0; s < 4; ++s) a[s] = *(const bf16x8*)(pa[s] + kk * 32);
#pragma unroll
        for (int t = 0; t < 4; ++t) b[t] = *(const bf16x8*)(pb[t] + kk * 32);
#pragma unroll
        for (int s = 0; s < 4; ++s)
#pragma unroll
            for (int t = 0; t < 4; ++t)
                acc[s][t] = __builtin_amdgcn_mfma_f32_16x16x32_bf16(a[s], b[t], acc[s][t], 0, 0, 0);
    }

#pragma unroll
    for (int t = 0; t < 4; ++t) {
        int col  = tn * 64 + t * 16 + m;
        float bv = bias[col];
#pragma unroll
        for (int s = 0; s < 4; ++s) {
            int row0 = tm * 64 + s * 16 + quad * 4;
#pragma unroll
            for (int r = 0; r < 4; ++r) {
                int row = row0 + r;
                if (row < n_nodes) {
                    float v = acc[s][t][r] + bv;
                    out[(size_t)row * ODIM + col] = fmaxf(v, 0.f);
                }
            }
        }
    }
}

extern "C" void kernel_launch(void* const* d_in, const int* in_sizes, int n_in,
                              void* d_out, int out_size, void* d_ws, size_t ws_size,
                              hipStream_t stream)
{
    const float* x    = (const float*)d_in[0];
    const int*   ei   = (const int*)d_in[1];
    const float* W    = (const float*)d_in[2];
    const float* bias = (const float*)d_in[3];

    int n_nodes = in_sizes[0] / IN_DIM;
    int n_edges = in_sizes[1] / 2;
    const int* src = ei;
    const int* dst = ei + n_edges;
    int n2 = 2 * n_nodes;

    // ws layout: deg[2N] | cursor[2N] | off[2N] | bsum[256] | csr[2E] | h | Wt
    char* ws = (char*)d_ws;
    int* deg    = (int*)ws;
    int* cursor = deg + n2;
    int* off    = cursor + n2;
    int* bsum   = off + n2;
    int* csr    = bsum + 256;
    __hip_bfloat16* h  = (__hip_bfloat16*)(csr + 2 * n_edges);
    __hip_bfloat16* Wt = h + (size_t)n_nodes * K3;

    // zero deg + cursor (contiguous)
    hipMemsetAsync(deg, 0, (size_t)2 * n2 * sizeof(int), stream);

    int eb = (n_edges + 255) / 256;
    sage_degree<<<eb, 256, 0, stream>>>(src, dst, deg, n_nodes, n_edges);

    int nblk = (n2 + 1023) / 1024;   // 98 for N=50000
    scan_partial<<<nblk, 256, 0, stream>>>(deg, off, bsum, n2);
    scan_bsum<<<1, 256, 0, stream>>>(bsum, nblk);
    scan_add<<<nblk, 256, 0, stream>>>(off, bsum, n2);

    sage_fill<<<eb, 256, 0, stream>>>(src, dst, off, cursor, csr, n_nodes, n_edges);

    sage_aggregate<<<(n_nodes + 3) / 4, 256, 0, stream>>>(x, csr, off, deg, h, n_nodes);

    sage_wt<<<(K3 * ODIM) / 256, 256, 0, stream>>>(W, Wt);

    int tiles_m = (n_nodes + 63) / 64;           // 782
    int waves   = tiles_m * (ODIM / 64);         // 12512
    sage_gemm<<<(waves + 3) / 4, 256, 0, stream>>>(h, Wt, bias, (float*)d_out, n_nodes, tiles_m);
}

// Round 3
// 565.204 us; speedup vs baseline: 3.1220x; 1.0589x over previous
//
#include <hip/hip_runtime.h>
#include <hip/hip_bf16.h>

// SAGEMean3: h = [x | mean_in | mean_out] (50000 x 384), out = relu(h @ W + b)
// R2: GEMM rewritten to m97-style 128x128 LDS-tiled structure:
//   - 256 threads/block = 2x2 waves, each wave owns a 64x64 subtile (4x4 MFMA accs)
//   - BK=64, K-loop 384/64 = 6 iters, global_load_lds width=16 staging
//   - XOR swizzle (seg ^ (row&7)) at stage time, un-swizzled at ds_read time:
//     spreads each quad across all 32 banks at 2-way aliasing (free per m136)
// Aggregation path (CSR build + gather) unchanged from R1.

typedef __attribute__((ext_vector_type(8))) short bf16x8;
typedef __attribute__((ext_vector_type(4))) float f32x4;

#define IN_DIM 128
#define K3 384
#define ODIM 1024

__global__ __launch_bounds__(256) void sage_degree(
    const int* __restrict__ src, const int* __restrict__ dst,
    int* __restrict__ deg, int n_nodes, int n_edges)
{
    int t = blockIdx.x * 256 + threadIdx.x;
    if (t >= n_edges) return;
    atomicAdd(deg + dst[t], 1);            // in-degree of dst
    atomicAdd(deg + n_nodes + src[t], 1);  // out-degree of src
}

// block-level exclusive scan: 1024 elements per 256-thread block
__global__ __launch_bounds__(256) void scan_partial(
    const int* __restrict__ deg, int* __restrict__ off, int* __restrict__ bsum, int n)
{
    __shared__ int s[256];
    int t = threadIdx.x;
    int base = blockIdx.x * 1024 + t * 4;
    int4 v = {0, 0, 0, 0};
    if (base + 3 < n) v = *(const int4*)(deg + base);
    else {
        if (base     < n) v.x = deg[base];
        if (base + 1 < n) v.y = deg[base + 1];
        if (base + 2 < n) v.z = deg[base + 2];
        if (base + 3 < n) v.w = deg[base + 3];
    }
    int tsum = v.x + v.y + v.z + v.w;
    s[t] = tsum;
    __syncthreads();
#pragma unroll
    for (int d = 1; d < 256; d <<= 1) {
        int add = (t >= d) ? s[t - d] : 0;
        __syncthreads();
        s[t] += add;
        __syncthreads();
    }
    int excl = s[t] - tsum;
    if (t == 255) bsum[blockIdx.x] = s[255];
    int e0 = excl, e1 = e0 + v.x, e2 = e1 + v.y, e3 = e2 + v.z;
    if (base     < n) off[base]     = e0;
    if (base + 1 < n) off[base + 1] = e1;
    if (base + 2 < n) off[base + 2] = e2;
    if (base + 3 < n) off[base + 3] = e3;
}

__global__ __launch_bounds__(256) void scan_bsum(int* __restrict__ bsum, int nblk)
{
    __shared__ int s[256];
    int t = threadIdx.x;
    int v = (t < nblk) ? bsum[t] : 0;
    s[t] = v;
    __syncthreads();
#pragma unroll
    for (int d = 1; d < 256; d <<= 1) {
        int add = (t >= d) ? s[t - d] : 0;
        __syncthreads();
        s[t] += add;
        __syncthreads();
    }
    if (t < nblk) bsum[t] = s[t] - v;   // exclusive
}

__global__ __launch_bounds__(256) void scan_add(
    int* __restrict__ off, const int* __restrict__ bsum, int n)
{
    int base = blockIdx.x * 1024 + threadIdx.x * 4;
    int b = bsum[blockIdx.x];
#pragma unroll
    for (int j = 0; j < 4; ++j)
        if (base + j < n) off[base + j] += b;
}

__global__ __launch_bounds__(256) void sage_fill(
    const int* __restrict__ src, const int* __restrict__ dst,
    const int* __restrict__ off, int* __restrict__ cursor,
    int* __restrict__ csr, int n_nodes, int n_edges)
{
    int t = blockIdx.x * 256 + threadIdx.x;
    if (t >= n_edges) return;
    int s = src[t];
    int d = dst[t];
    int p0 = atomicAdd(cursor + d, 1);
    csr[off[d] + p0] = s;                        // in-neighbor of d
    int p1 = atomicAdd(cursor + n_nodes + s, 1);
    csr[off[n_nodes + s] + p1] = d;              // out-neighbor of s
}

// one wave per node: gather + mean both directions, write bf16 h row
__global__ __launch_bounds__(256) void sage_aggregate(
    const float* __restrict__ x, const int* __restrict__ csr,
    const int* __restrict__ off, const int* __restrict__ deg,
    __hip_bfloat16* __restrict__ h, int n_nodes)
{
    int wid  = (int)((blockIdx.x * 256 + threadIdx.x) >> 6);
    int lane = threadIdx.x & 63;
    if (wid >= n_nodes) return;
    int i = wid;

    float2 ai = {0.f, 0.f}, ao = {0.f, 0.f};
    int b0 = off[i],           d0 = deg[i];
    int b1 = off[n_nodes + i], d1 = deg[n_nodes + i];

    int e = 0;
    for (; e + 1 < d0; e += 2) {
        int nb0 = csr[b0 + e], nb1 = csr[b0 + e + 1];
        float2 v0 = *(const float2*)(x + (size_t)nb0 * IN_DIM + lane * 2);
        float2 v1 = *(const float2*)(x + (size_t)nb1 * IN_DIM + lane * 2);
        ai.x += v0.x + v1.x; ai.y += v0.y + v1.y;
    }
    if (e < d0) {
        int nb = csr[b0 + e];
        float2 v = *(const float2*)(x + (size_t)nb * IN_DIM + lane * 2);
        ai.x += v.x; ai.y += v.y;
    }
    e = 0;
    for (; e + 1 < d1; e += 2) {
        int nb0 = csr[b1 + e], nb1 = csr[b1 + e + 1];
        float2 v0 = *(const float2*)(x + (size_t)nb0 * IN_DIM + lane * 2);
        float2 v1 = *(const float2*)(x + (size_t)nb1 * IN_DIM + lane * 2);
        ao.x += v0.x + v1.x; ao.y += v0.y + v1.y;
    }
    if (e < d1) {
        int nb = csr[b1 + e];
        float2 v = *(const float2*)(x + (size_t)nb * IN_DIM + lane * 2);
        ao.x += v.x; ao.y += v.y;
    }

    float inv0 = 1.0f / (float)max(d0, 1);
    float inv1 = 1.0f / (float)max(d1, 1);
    float2 xv = *(const float2*)(x + (size_t)i * IN_DIM + lane * 2);

    __hip_bfloat162* hp = (__hip_bfloat162*)(h + (size_t)i * K3);
    __hip_bfloat162 p;
    p.x = __float2bfloat16(xv.x);        p.y = __float2bfloat16(xv.y);
    hp[lane] = p;
    p.x = __float2bfloat16(ai.x * inv0); p.y = __float2bfloat16(ai.y * inv0);
    hp[64 + lane] = p;
    p.x = __float2bfloat16(ao.x * inv1); p.y = __float2bfloat16(ao.y * inv1);
    hp[128 + lane] = p;
}

__global__ __launch_bounds__(256) void sage_wt(
    const float* __restrict__ W, __hip_bfloat16* __restrict__ Wt)
{
    int tid = blockIdx.x * 256 + threadIdx.x;   // over K3*ODIM
    int k  = tid / ODIM;
    int nn = tid % ODIM;
    Wt[(size_t)nn * K3 + k] = __float2bfloat16(W[tid]);
}

// 128x128 block tile, 2x2 waves of 64x64, BK=64, global_load_lds staging,
// XOR-swizzled LDS layout. A: h[m][k], B: Wt[n][k] (both K-contiguous bf16).
__global__ __launch_bounds__(256) void sage_gemm(
    const __hip_bfloat16* __restrict__ h, const __hip_bfloat16* __restrict__ Wt,
    const float* __restrict__ bias, float* __restrict__ out, int n_nodes)
{
    __shared__ __hip_bfloat16 Asm[128 * 64];   // 16 KB
    __shared__ __hip_bfloat16 Bsm[128 * 64];   // 16 KB

    int t    = threadIdx.x;
    int wave = t >> 6;
    int lane = t & 63;
    int tn   = blockIdx.x & 7;       // 8 n-tiles of 128
    int tm   = blockIdx.x >> 3;      // 391 m-tiles of 128
    int m0   = tm * 128;
    int n0   = tn * 128;
    int wm   = wave >> 1;            // 0..1
    int wn   = wave & 1;             // 0..1
    int m    = lane & 15;
    int quad = lane >> 4;

    // Staging geometry: tile = 128 rows x 8 ksegs of 16B; chunk = row*8 + seg.
    // 1024 chunks, 4 rounds x 256 threads. LDS slot 'seg' of row r holds
    // global kseg (seg ^ (r&7)).
    f32x4 acc[4][4];
#pragma unroll
    for (int s = 0; s < 4; ++s)
#pragma unroll
        for (int u = 0; u < 4; ++u) acc[s][u] = (f32x4){0.f, 0.f, 0.f, 0.f};

    for (int kt = 0; kt < 6; ++kt) {
        int k0 = kt * 64;
        __syncthreads();             // previous iter's LDS reads done
#pragma unroll
        for (int r = 0; r < 4; ++r) {
            int chunk = r * 256 + t;
            int row   = chunk >> 3;
            int seg   = chunk & 7;
            int g     = seg ^ (row & 7);
            int grow  = m0 + row;
            if (grow >= n_nodes) grow = n_nodes - 1;   // dup-read; stores guarded
            const __hip_bfloat16* gpA = h  + (size_t)grow * K3 + k0 + g * 8;
            const __hip_bfloat16* gpB = Wt + (size_t)(n0 + row) * K3 + k0 + g * 8;
            // wave-uniform LDS base + lane*16
            __hip_bfloat16* lpA = Asm + (size_t)(r * 256 + wave * 64) * 8;
            __hip_bfloat16* lpB = Bsm + (size_t)(r * 256 + wave * 64) * 8;
            __builtin_amdgcn_global_load_lds(gpA, lpA, 16, 0, 0);
            __builtin_amdgcn_global_load_lds(gpB, lpB, 16, 0, 0);
        }
        __syncthreads();             // staging visible to all waves

#pragma unroll
        for (int ks = 0; ks < 2; ++ks) {
            bf16x8 a[4], b[4];
            int slot = (ks * 4 + quad) ^ (m & 7);
#pragma unroll
            for (int s = 0; s < 4; ++s) {
                int row = wm * 64 + s * 16 + m;
                a[s] = *(const bf16x8*)&Asm[row * 64 + slot * 8];
            }
#pragma unroll
            for (int u = 0; u < 4; ++u) {
                int row = wn * 64 + u * 16 + m;
                b[u] = *(const bf16x8*)&Bsm[row * 64 + slot * 8];
            }
#pragma unroll
            for (int s = 0; s < 4; ++s)
#pragma unroll
                for (int u = 0; u < 4; ++u)
                    acc[s][u] = __builtin_amdgcn_mfma_f32_16x16x32_bf16(a[s], b[u], acc[s][u], 0, 0, 0);
        }
    }

#pragma unroll
    for (int u = 0; u < 4; ++u) {
        int col  = n0 + wn * 64 + u * 16 + m;
        float bv = bias[col];
#pragma unroll
        for (int s = 0; s < 4; ++s) {
            int row0 = m0 + wm * 64 + s * 16 + quad * 4;
#pragma unroll
            for (int r = 0; r < 4; ++r) {
                int row = row0 + r;
                if (row < n_nodes) {
                    float v = acc[s][u][r] + bv;
                    out[(size_t)row * ODIM + col] = fmaxf(v, 0.f);
                }
            }
        }
    }
}

extern "C" void kernel_launch(void* const* d_in, const int* in_sizes, int n_in,
                              void* d_out, int out_size, void* d_ws, size_t ws_size,
                              hipStream_t stream)
{
    const float* x    = (const float*)d_in[0];
    const int*   ei   = (const int*)d_in[1];
    const float* W    = (const float*)d_in[2];
    const float* bias = (const float*)d_in[3];

    int n_nodes = in_sizes[0] / IN_DIM;
    int n_edges = in_sizes[1] / 2;
    const int* src = ei;
    const int* dst = ei + n_edges;
    int n2 = 2 * n_nodes;

    // ws layout: deg[2N] | cursor[2N] | off[2N] | bsum[256] | csr[2E] | h | Wt
    char* ws = (char*)d_ws;
    int* deg    = (int*)ws;
    int* cursor = deg + n2;
    int* off    = cursor + n2;
    int* bsum   = off + n2;
    int* csr    = bsum + 256;
    __hip_bfloat16* h  = (__hip_bfloat16*)(csr + 2 * n_edges);
    __hip_bfloat16* Wt = h + (size_t)n_nodes * K3;

    // zero deg + cursor (contiguous)
    hipMemsetAsync(deg, 0, (size_t)2 * n2 * sizeof(int), stream);

    int eb = (n_edges + 255) / 256;
    sage_degree<<<eb, 256, 0, stream>>>(src, dst, deg, n_nodes, n_edges);

    int nblk = (n2 + 1023) / 1024;   // 98 for N=50000
    scan_partial<<<nblk, 256, 0, stream>>>(deg, off, bsum, n2);
    scan_bsum<<<1, 256, 0, stream>>>(bsum, nblk);
    scan_add<<<nblk, 256, 0, stream>>>(off, bsum, n2);

    sage_fill<<<eb, 256, 0, stream>>>(src, dst, off, cursor, csr, n_nodes, n_edges);

    sage_aggregate<<<(n_nodes + 3) / 4, 256, 0, stream>>>(x, csr, off, deg, h, n_nodes);

    sage_wt<<<(K3 * ODIM) / 256, 256, 0, stream>>>(W, Wt);

    int tiles_m = (n_nodes + 127) / 128;         // 391
    int blocks  = tiles_m * (ODIM / 128);        // 391 * 8 = 3128
    sage_gemm<<<blocks, 256, 0, stream>>>(h, Wt, bias, (float*)d_out, n_nodes);
}

// Round 4
// 526.071 us; speedup vs baseline: 3.3542x; 1.0744x over previous
//
#include <hip/hip_runtime.h>
#include <hip/hip_bf16.h>

// SAGEMean3: h = [x | mean_in | mean_out] (50000 x 384), out = relu(h @ W + b)
// R4:
//  - GEMM: 128x128 block tile, BK=32, DOUBLE-BUFFERED global_load_lds (32 KB LDS
//    total -> 4 blocks/CU kept), __launch_bounds__(256,4), XOR swizzle seg^(row&3),
//    uniform-branch epilogue. Stage(k+1) issued right after barrier, overlapped
//    with compute(k) -> vmcnt(0) drain at barrier is pre-hidden.
//  - Aggregation gathers bf16 (xb) instead of fp32: traffic halved. Convert kernel
//    also fills h[:,0:128].
//  - scan_add initializes cursor=off so fill needs no scattered off reads.

typedef __attribute__((ext_vector_type(8))) short bf16x8;
typedef __attribute__((ext_vector_type(4))) float f32x4;

#define IN_DIM 128
#define K3 384
#define ODIM 1024

__global__ __launch_bounds__(256) void sage_degree(
    const int* __restrict__ src, const int* __restrict__ dst,
    int* __restrict__ deg, int n_nodes, int n_edges)
{
    int t = blockIdx.x * 256 + threadIdx.x;
    if (t >= n_edges) return;
    atomicAdd(deg + dst[t], 1);            // in-degree of dst
    atomicAdd(deg + n_nodes + src[t], 1);  // out-degree of src
}

// fp32 x -> bf16 xb, and fill h[:, 0:128]
__global__ __launch_bounds__(256) void sage_convert(
    const float* __restrict__ x, __hip_bfloat16* __restrict__ xb,
    __hip_bfloat16* __restrict__ h, int n_nodes)
{
    int tid = blockIdx.x * 256 + threadIdx.x;
    if (tid >= n_nodes * IN_DIM) return;
    int i = tid >> 7, d = tid & 127;
    __hip_bfloat16 v = __float2bfloat16(x[tid]);
    xb[tid] = v;
    h[(size_t)i * K3 + d] = v;
}

// block-level exclusive scan: 1024 elements per 256-thread block
__global__ __launch_bounds__(256) void scan_partial(
    const int* __restrict__ deg, int* __restrict__ off, int* __restrict__ bsum, int n)
{
    __shared__ int s[256];
    int t = threadIdx.x;
    int base = blockIdx.x * 1024 + t * 4;
    int4 v = {0, 0, 0, 0};
    if (base + 3 < n) v = *(const int4*)(deg + base);
    else {
        if (base     < n) v.x = deg[base];
        if (base + 1 < n) v.y = deg[base + 1];
        if (base + 2 < n) v.z = deg[base + 2];
        if (base + 3 < n) v.w = deg[base + 3];
    }
    int tsum = v.x + v.y + v.z + v.w;
    s[t] = tsum;
    __syncthreads();
#pragma unroll
    for (int d = 1; d < 256; d <<= 1) {
        int add = (t >= d) ? s[t - d] : 0;
        __syncthreads();
        s[t] += add;
        __syncthreads();
    }
    int excl = s[t] - tsum;
    if (t == 255) bsum[blockIdx.x] = s[255];
    int e0 = excl, e1 = e0 + v.x, e2 = e1 + v.y, e3 = e2 + v.z;
    if (base     < n) off[base]     = e0;
    if (base + 1 < n) off[base + 1] = e1;
    if (base + 2 < n) off[base + 2] = e2;
    if (base + 3 < n) off[base + 3] = e3;
}

__global__ __launch_bounds__(256) void scan_bsum(int* __restrict__ bsum, int nblk)
{
    __shared__ int s[256];
    int t = threadIdx.x;
    int v = (t < nblk) ? bsum[t] : 0;
    s[t] = v;
    __syncthreads();
#pragma unroll
    for (int d = 1; d < 256; d <<= 1) {
        int add = (t >= d) ? s[t - d] : 0;
        __syncthreads();
        s[t] += add;
        __syncthreads();
    }
    if (t < nblk) bsum[t] = s[t] - v;   // exclusive
}

// add block offset; also initialize cursor = off (for fill)
__global__ __launch_bounds__(256) void scan_add(
    int* __restrict__ off, int* __restrict__ cursor,
    const int* __restrict__ bsum, int n)
{
    int base = blockIdx.x * 1024 + threadIdx.x * 4;
    int b = bsum[blockIdx.x];
#pragma unroll
    for (int j = 0; j < 4; ++j)
        if (base + j < n) {
            int v = off[base + j] + b;
            off[base + j]    = v;
            cursor[base + j] = v;
        }
}

__global__ __launch_bounds__(256) void sage_fill(
    const int* __restrict__ src, const int* __restrict__ dst,
    int* __restrict__ cursor, int* __restrict__ csr, int n_nodes, int n_edges)
{
    int t = blockIdx.x * 256 + threadIdx.x;
    if (t >= n_edges) return;
    int s = src[t];
    int d = dst[t];
    int p0 = atomicAdd(cursor + d, 1);
    csr[p0] = s;                         // in-neighbor of d
    int p1 = atomicAdd(cursor + n_nodes + s, 1);
    csr[p1] = d;                         // out-neighbor of s
}

// one wave per node: bf16 gathers, fp32 accumulate, write h[:,128:384]
__global__ __launch_bounds__(256) void sage_aggregate(
    const __hip_bfloat16* __restrict__ xb, const int* __restrict__ csr,
    const int* __restrict__ off, const int* __restrict__ deg,
    __hip_bfloat16* __restrict__ h, int n_nodes)
{
    int wid  = (int)((blockIdx.x * 256 + threadIdx.x) >> 6);
    int lane = threadIdx.x & 63;
    if (wid >= n_nodes) return;
    int i = wid;

    float2 ai = {0.f, 0.f}, ao = {0.f, 0.f};
    int b0 = off[i],           d0 = deg[i];
    int b1 = off[n_nodes + i], d1 = deg[n_nodes + i];

#define GATHER(nb, acc) { \
    __hip_bfloat162 v = ((const __hip_bfloat162*)(xb + (size_t)(nb) * IN_DIM))[lane]; \
    acc.x += __low2float(v); acc.y += __high2float(v); }

    int e = 0;
    for (; e + 3 < d0; e += 4) {
        int a0 = csr[b0 + e], a1 = csr[b0 + e + 1], a2 = csr[b0 + e + 2], a3 = csr[b0 + e + 3];
        GATHER(a0, ai) GATHER(a1, ai) GATHER(a2, ai) GATHER(a3, ai)
    }
    for (; e < d0; ++e) { int a0 = csr[b0 + e]; GATHER(a0, ai) }
    e = 0;
    for (; e + 3 < d1; e += 4) {
        int a0 = csr[b1 + e], a1 = csr[b1 + e + 1], a2 = csr[b1 + e + 2], a3 = csr[b1 + e + 3];
        GATHER(a0, ao) GATHER(a1, ao) GATHER(a2, ao) GATHER(a3, ao)
    }
    for (; e < d1; ++e) { int a0 = csr[b1 + e]; GATHER(a0, ao) }
#undef GATHER

    float inv0 = 1.0f / (float)max(d0, 1);
    float inv1 = 1.0f / (float)max(d1, 1);

    __hip_bfloat162* hp = (__hip_bfloat162*)(h + (size_t)i * K3);
    __hip_bfloat162 p;
    p.x = __float2bfloat16(ai.x * inv0); p.y = __float2bfloat16(ai.y * inv0);
    hp[64 + lane] = p;
    p.x = __float2bfloat16(ao.x * inv1); p.y = __float2bfloat16(ao.y * inv1);
    hp[128 + lane] = p;
}

__global__ __launch_bounds__(256) void sage_wt(
    const float* __restrict__ W, __hip_bfloat16* __restrict__ Wt)
{
    int tid = blockIdx.x * 256 + threadIdx.x;   // over K3*ODIM
    int k  = tid / ODIM;
    int nn = tid % ODIM;
    Wt[(size_t)nn * K3 + k] = __float2bfloat16(W[tid]);
}

// 128x128 block tile, 2x2 waves of 64x64, BK=32, double-buffered LDS staging.
// Stage geometry per op per ktile: 128 rows x 4 ksegs(16B) = 512 chunks,
// 2 rounds x 256 threads. LDS slot seg of row r holds global kseg seg^(r&3).
__global__ __launch_bounds__(256, 4) void sage_gemm(
    const __hip_bfloat16* __restrict__ h, const __hip_bfloat16* __restrict__ Wt,
    const float* __restrict__ bias, float* __restrict__ out, int n_nodes)
{
    __shared__ __hip_bfloat16 Asm[2][128 * 32];   // 2 x 8 KB
    __shared__ __hip_bfloat16 Bsm[2][128 * 32];   // 2 x 8 KB

    int t    = threadIdx.x;
    int wave = t >> 6;
    int lane = t & 63;
    int tn   = blockIdx.x & 7;       // 8 n-tiles of 128
    int tm   = blockIdx.x >> 3;      // 391 m-tiles of 128
    int m0   = tm * 128;
    int n0   = tn * 128;
    int wm   = wave >> 1;
    int wn   = wave & 1;
    int m    = lane & 15;
    int quad = lane >> 4;

    // per-thread staging addresses: chunks t and t+256 (rows r, r+64; same seg)
    int srow = t >> 2;
    int seg  = t & 3;
    int g    = seg ^ (srow & 3);     // (srow+64)&3 == srow&3
    int ga0  = m0 + srow;       if (ga0 >= n_nodes) ga0 = n_nodes - 1;
    int ga1  = m0 + srow + 64;  if (ga1 >= n_nodes) ga1 = n_nodes - 1;
    const __hip_bfloat16* gA0 = h  + (size_t)ga0 * K3 + g * 8;
    const __hip_bfloat16* gA1 = h  + (size_t)ga1 * K3 + g * 8;
    const __hip_bfloat16* gB0 = Wt + (size_t)(n0 + srow) * K3 + g * 8;
    const __hip_bfloat16* gB1 = Wt + (size_t)(n0 + srow + 64) * K3 + g * 8;
    // wave-uniform LDS bases (+ lane*16 implicit)
    int l0 = (0 * 256 + wave * 64) * 8;
    int l1 = (1 * 256 + wave * 64) * 8;

    f32x4 acc[4][4];
#pragma unroll
    for (int s = 0; s < 4; ++s)
#pragma unroll
        for (int u = 0; u < 4; ++u) acc[s][u] = (f32x4){0.f, 0.f, 0.f, 0.f};

    // prologue: stage ktile 0 into buffer 0
    __builtin_amdgcn_global_load_lds(gA0, &Asm[0][l0], 16, 0, 0);
    __builtin_amdgcn_global_load_lds(gA1, &Asm[0][l1], 16, 0, 0);
    __builtin_amdgcn_global_load_lds(gB0, &Bsm[0][l0], 16, 0, 0);
    __builtin_amdgcn_global_load_lds(gB1, &Bsm[0][l1], 16, 0, 0);

    int slot = quad ^ (m & 3);
#pragma unroll
    for (int kt = 0; kt < 12; ++kt) {
        int p = kt & 1;
        __syncthreads();   // drains stage(kt) [in flight for one full compute] + prior reads
        if (kt < 11) {     // stage kt+1 into the other buffer, overlapped with compute
            int koff = (kt + 1) * 32;
            __builtin_amdgcn_global_load_lds(gA0 + koff, &Asm[p ^ 1][l0], 16, 0, 0);
            __builtin_amdgcn_global_load_lds(gA1 + koff, &Asm[p ^ 1][l1], 16, 0, 0);
            __builtin_amdgcn_global_load_lds(gB0 + koff, &Bsm[p ^ 1][l0], 16, 0, 0);
            __builtin_amdgcn_global_load_lds(gB1 + koff, &Bsm[p ^ 1][l1], 16, 0, 0);
        }
        bf16x8 a[4], b[4];
#pragma unroll
        for (int s = 0; s < 4; ++s) {
            int row = wm * 64 + s * 16 + m;
            a[s] = *(const bf16x8*)&Asm[p][row * 32 + slot * 8];
        }
#pragma unroll
        for (int u = 0; u < 4; ++u) {
            int row = wn * 64 + u * 16 + m;
            b[u] = *(const bf16x8*)&Bsm[p][row * 32 + slot * 8];
        }
#pragma unroll
        for (int s = 0; s < 4; ++s)
#pragma unroll
            for (int u = 0; u < 4; ++u)
                acc[s][u] = __builtin_amdgcn_mfma_f32_16x16x32_bf16(a[s], b[u], acc[s][u], 0, 0, 0);
    }

    bool full = (m0 + 128 <= n_nodes);   // uniform per block
    if (full) {
#pragma unroll
        for (int u = 0; u < 4; ++u) {
            int col  = n0 + wn * 64 + u * 16 + m;
            float bv = bias[col];
#pragma unroll
            for (int s = 0; s < 4; ++s) {
                int r0 = m0 + wm * 64 + s * 16 + quad * 4;
#pragma unroll
                for (int r = 0; r < 4; ++r)
                    out[(size_t)(r0 + r) * ODIM + col] = fmaxf(acc[s][u][r] + bv, 0.f);
            }
        }
    } else {
#pragma unroll
        for (int u = 0; u < 4; ++u) {
            int col  = n0 + wn * 64 + u * 16 + m;
            float bv = bias[col];
#pragma unroll
            for (int s = 0; s < 4; ++s) {
                int r0 = m0 + wm * 64 + s * 16 + quad * 4;
#pragma unroll
                for (int r = 0; r < 4; ++r)
                    if (r0 + r < n_nodes)
                        out[(size_t)(r0 + r) * ODIM + col] = fmaxf(acc[s][u][r] + bv, 0.f);
            }
        }
    }
}

extern "C" void kernel_launch(void* const* d_in, const int* in_sizes, int n_in,
                              void* d_out, int out_size, void* d_ws, size_t ws_size,
                              hipStream_t stream)
{
    const float* x    = (const float*)d_in[0];
    const int*   ei   = (const int*)d_in[1];
    const float* W    = (const float*)d_in[2];
    const float* bias = (const float*)d_in[3];

    int n_nodes = in_sizes[0] / IN_DIM;
    int n_edges = in_sizes[1] / 2;
    const int* src = ei;
    const int* dst = ei + n_edges;
    int n2 = 2 * n_nodes;

    // ws layout: deg[2N] | cursor[2N] | off[2N] | bsum[256] | csr[2E] | h | Wt | xb
    char* ws = (char*)d_ws;
    int* deg    = (int*)ws;
    int* cursor = deg + n2;
    int* off    = cursor + n2;
    int* bsum   = off + n2;
    int* csr    = bsum + 256;
    __hip_bfloat16* h  = (__hip_bfloat16*)(csr + 2 * n_edges);
    __hip_bfloat16* Wt = h  + (size_t)n_nodes * K3;
    __hip_bfloat16* xb = Wt + (size_t)K3 * ODIM;

    hipMemsetAsync(deg, 0, (size_t)n2 * sizeof(int), stream);

    int eb = (n_edges + 255) / 256;
    sage_degree<<<eb, 256, 0, stream>>>(src, dst, deg, n_nodes, n_edges);

    sage_convert<<<(n_nodes * IN_DIM + 255) / 256, 256, 0, stream>>>(x, xb, h, n_nodes);

    int nblk = (n2 + 1023) / 1024;   // 98 for N=50000
    scan_partial<<<nblk, 256, 0, stream>>>(deg, off, bsum, n2);
    scan_bsum<<<1, 256, 0, stream>>>(bsum, nblk);
    scan_add<<<nblk, 256, 0, stream>>>(off, cursor, bsum, n2);

    sage_fill<<<eb, 256, 0, stream>>>(src, dst, cursor, csr, n_nodes, n_edges);

    sage_aggregate<<<(n_nodes + 3) / 4, 256, 0, stream>>>(xb, csr, off, deg, h, n_nodes);

    sage_wt<<<(K3 * ODIM) / 256, 256, 0, stream>>>(W, Wt);

    int tiles_m = (n_nodes + 127) / 128;         // 391
    int blocks  = tiles_m * (ODIM / 128);        // 3128
    sage_gemm<<<blocks, 256, 0, stream>>>(h, Wt, bias, (float*)d_out, n_nodes);
}